// Round 22
// baseline (148.137 us; speedup 1.0000x reference)
//
#include <hip/hip_runtime.h>
#include <math.h>

// AttentionLayer: x[16,2048,64] f32 -> QKV -> softmax(QK^T/8)V -> fc+residual -> LN.
// R21 (PASSED, 101.0us; K2=89.0): LDS pipe ~95% saturated (3170 of 3340 cyc/CU-tile);
// K-frag ds_reads are 36% of it and 4x-duplicated across wq waves. This round: K-frags
// PREFETCHED INTO REGISTERS from the L2-resident global K planes (XCD-local after R21
// swizzle) -- K LDS staging deleted. V/P LDS paths, barriers, numerics byte-identical.
// Expected new bound: MFMA pipe (2790 cyc/CU-tile).

#define HEADS 16
#define SEQ   2048
#define DIM   64
#define NT    32

typedef short short8 __attribute__((ext_vector_type(8)));   // 8 x bf16 bits
typedef short short4v __attribute__((ext_vector_type(4)));
typedef float f32x4  __attribute__((ext_vector_type(4)));

// 32 MB module scratch, fully rewritten by K1 every launch (replay-deterministic).
__device__ __align__(16) short g_Qh [(size_t)HEADS * SEQ * DIM];
__device__ __align__(16) short g_Qm [(size_t)HEADS * SEQ * DIM];
__device__ __align__(16) short g_Ql [(size_t)HEADS * SEQ * DIM];
__device__ __align__(16) short g_Kh [(size_t)HEADS * SEQ * DIM];
__device__ __align__(16) short g_Km [(size_t)HEADS * SEQ * DIM];
__device__ __align__(16) short g_Kl [(size_t)HEADS * SEQ * DIM];
__device__ __align__(16) short g_VTh[(size_t)HEADS * DIM * SEQ];   // V^T [head][e][s]
__device__ __align__(16) short g_VTm[(size_t)HEADS * DIM * SEQ];

static __device__ __forceinline__ short f2bf(float f) {
  union { float f; unsigned u; } cv; cv.f = f;
  unsigned u = cv.u;
  unsigned r = (u + 0x7fffu + ((u >> 16) & 1u)) >> 16;   // RNE
  return (short)r;
}
static __device__ __forceinline__ float bf2f(short s) {
  union { unsigned u; float f; } cv; cv.u = ((unsigned)(unsigned short)s) << 16;
  return cv.f;
}
static __device__ __forceinline__ void split2(float v, short* h, short* l) {
  short hh = f2bf(v);
  *h = hh;
  *l = f2bf(v - bf2f(hh));
}
static __device__ __forceinline__ short2 split2v(float v) {
  short hh = f2bf(v);
  short ll = f2bf(v - bf2f(hh));
  return make_short2(hh, ll);
}
// EXACT: v == h+m+l for normal-range f32 (24 = 8+8+8 mantissa bits).
static __device__ __forceinline__ void split3(float v, short* h, short* m, short* l) {
  short hh = f2bf(v);
  float r  = v - bf2f(hh);
  short mm = f2bf(r);
  *h = hh; *m = mm;
  *l = f2bf(r - bf2f(mm));
}
// 2-plane truncation split (~3 VALU): v = h + m + O(2^-16 v).
static __device__ __forceinline__ void split2_bits(float v, short* h, short* m) {
  union { float f; unsigned u; } a; a.f = v;
  unsigned hu = a.u & 0xFFFF0000u;
  union { unsigned u; float f; } hf; hf.u = hu;
  union { float f; unsigned u; } b; b.f = v - hf.f;     // exact residual
  *h = (short)(hu >> 16); *m = (short)(b.u >> 16);
}

// ---------------- K1: fp32 VALU projections (validated), split writeout --------------
__global__ __launch_bounds__(256) void qkv_valu(
    const float* __restrict__ x,  const float* __restrict__ WQ,
    const float* __restrict__ WK, const float* __restrict__ WV)
{
  __shared__ float XB [64][68];
  __shared__ float WTQ[64][68];
  __shared__ float WTK[64][68];
  __shared__ float WTV[64][68];
  const int t    = threadIdx.x;
  const int bid  = (int)(blockIdx.x & 7) * 64 + (int)(blockIdx.x >> 3);  // XCD swizzle (512%8==0)
  const int head = bid >> 5;
  const int s0   = (bid & 31) * 64;
  const float* xp = x + ((size_t)head * SEQ + s0) * DIM;

  for (int i = t; i < 1024; i += 256) {
    int row = i >> 4, c4 = (i & 15) << 2;
    *(float4*)&XB[row][c4] = *(const float4*)(xp + row * 64 + c4);
    float4 a = *(const float4*)(WQ + row * 64 + c4);
    WTQ[c4][row] = a.x; WTQ[c4+1][row] = a.y; WTQ[c4+2][row] = a.z; WTQ[c4+3][row] = a.w;
    float4 b = *(const float4*)(WK + row * 64 + c4);
    WTK[c4][row] = b.x; WTK[c4+1][row] = b.y; WTK[c4+2][row] = b.z; WTK[c4+3][row] = b.w;
    float4 d = *(const float4*)(WV + row * 64 + c4);
    WTV[c4][row] = d.x; WTV[c4+1][row] = d.y; WTV[c4+2][row] = d.z; WTV[c4+3][row] = d.w;
  }
  __syncthreads();

  const int jj = t >> 2;
  const int eg = (t & 3) * 16;
  float aq[16], ak[16], av[16];
#pragma unroll
  for (int c = 0; c < 16; ++c) { aq[c] = 0.f; ak[c] = 0.f; av[c] = 0.f; }
  for (int d = 0; d < 64; ++d) {
    float xv = XB[jj][d];
#pragma unroll
    for (int c4 = 0; c4 < 16; c4 += 4) {
      float4 wq = *(const float4*)&WTQ[d][eg + c4];
      aq[c4]   += xv * wq.x; aq[c4+1] += xv * wq.y; aq[c4+2] += xv * wq.z; aq[c4+3] += xv * wq.w;
      float4 wk = *(const float4*)&WTK[d][eg + c4];
      ak[c4]   += xv * wk.x; ak[c4+1] += xv * wk.y; ak[c4+2] += xv * wk.z; ak[c4+3] += xv * wk.w;
      float4 wv = *(const float4*)&WTV[d][eg + c4];
      av[c4]   += xv * wv.x; av[c4+1] += xv * wv.y; av[c4+2] += xv * wv.z; av[c4+3] += xv * wv.w;
    }
  }
  const size_t rowi  = ((size_t)head * SEQ + s0 + jj) * DIM + eg;
  const size_t vbase = (size_t)head * DIM * SEQ + s0 + jj;
  short qh_[16], qm_[16], ql_[16], kh_[16], km_[16], kl_[16];
#pragma unroll
  for (int c = 0; c < 16; ++c) {
    split3(aq[c] * 0.125f, &qh_[c], &qm_[c], &ql_[c]);
    split3(ak[c],          &kh_[c], &km_[c], &kl_[c]);
    size_t vb = vbase + (size_t)(eg + c) * SEQ;
    split2(av[c], &g_VTh[vb], &g_VTm[vb]);      // V needs only 2 planes (PV 3-term)
  }
#pragma unroll
  for (int half = 0; half < 2; ++half) {
    *(short8*)(g_Qh + rowi + half*8) = *(const short8*)&qh_[half*8];
    *(short8*)(g_Qm + rowi + half*8) = *(const short8*)&qm_[half*8];
    *(short8*)(g_Ql + rowi + half*8) = *(const short8*)&ql_[half*8];
    *(short8*)(g_Kh + rowi + half*8) = *(const short8*)&kh_[half*8];
    *(short8*)(g_Km + rowi + half*8) = *(const short8*)&km_[half*8];
    *(short8*)(g_Kl + rowi + half*8) = *(const short8*)&kl_[half*8];
  }
}

// -------- K2: flash attention (reg-resident K frags, LDS V+P) + MFMA fc + LN --------
__global__ __launch_bounds__(512) void attn_mfma(
    const float* __restrict__ x, const float* __restrict__ Wfc, float* __restrict__ out)
{
  __shared__ short Vth[64][72],  Vtm[64][72];                 // V^T tile planes [e][key]
  __shared__ short Pth[128][72], Ptm[128][72], Ptl[128][72];  // P(h,m) | combine | ctx
  const int t    = threadIdx.x;
  const int w    = t >> 6, lane = t & 63;
  const int r16  = lane & 15, g = lane >> 4;
  const int wq   = w & 3;          // q sub-block (32 rows)
  const int wk   = (w >> 2) & 1;   // key half (32 keys)
  const int bid  = (int)(blockIdx.x & 7) * 32 + (int)(blockIdx.x >> 3);  // XCD swizzle
  const int head = bid >> 4;       // each XCD owns 2 whole heads (~L2-fit)
  const int q0   = (bid & 15) * 128;
  const short* Kph = g_Kh  + (size_t)head * SEQ * DIM;
  const short* Kpm = g_Km  + (size_t)head * SEQ * DIM;
  const short* Kpl = g_Kl  + (size_t)head * SEQ * DIM;
  const short* Vph = g_VTh + (size_t)head * DIM * SEQ;
  const short* Vpm = g_VTm + (size_t)head * DIM * SEQ;
  const int srow = t >> 3, scol = (t & 7) * 8;

  // Q B-frags (col=q=r16, k=e): direct from global planes (validated pattern)
  short8 qfh[2][2], qfm[2][2], qfl[2][2];   // [qs][dh]
#pragma unroll
  for (int qs = 0; qs < 2; ++qs) {
    const size_t qrow = ((size_t)head * SEQ + q0 + wq*32 + qs*16 + r16) * DIM;
#pragma unroll
    for (int dh = 0; dh < 2; ++dh) {
      qfh[qs][dh] = *(const short8*)(g_Qh + qrow + dh*32 + g*8);
      qfm[qs][dh] = *(const short8*)(g_Qm + qrow + dh*32 + g*8);
      qfl[qs][dh] = *(const short8*)(g_Ql + qrow + dh*32 + g*8);
    }
  }

  // K A-frag base for this wave: row = kt*64 + wk*32 + n*16 + r16, cols dh*32+g*8
  const size_t kfbase = (size_t)(wk*32 + r16) * 64 + g*8;

  // prologue: prefetch V(0) regs + K(0) frag regs
  short8 rvh, rvm;
  short8 kfh[2][2], kfm[2][2], kfl[2][2];   // [n][dh] frags for current tile
  {
    size_t vo = (size_t)srow * SEQ + scol;
    rvh = *(const short8*)(Vph + vo);
    rvm = *(const short8*)(Vpm + vo);
#pragma unroll
    for (int n = 0; n < 2; ++n)
#pragma unroll
      for (int dh = 0; dh < 2; ++dh) {
        size_t ko = kfbase + (size_t)(n*16) * 64 + dh*32;
        kfh[n][dh] = *(const short8*)(Kph + ko);
        kfm[n][dh] = *(const short8*)(Kpm + ko);
        kfl[n][dh] = *(const short8*)(Kpl + ko);
      }
  }

  f32x4 o[2][4];                 // [qs][ne]
  float lacc[2];
#pragma unroll
  for (int qs = 0; qs < 2; ++qs) {
    lacc[qs] = 0.f;
#pragma unroll
    for (int ne = 0; ne < 4; ++ne) o[qs][ne] = (f32x4){0.f,0.f,0.f,0.f};
  }

  for (int kt = 0; kt < NT; ++kt) {
    __syncthreads();                              // prior tile's V reads done
    *(short8*)&Vth[srow][scol] = rvh;
    *(short8*)&Vtm[srow][scol] = rvm;
    __syncthreads();                              // V(kt) visible

    // swapped QK^T: 6-term (validated), K frags from REGISTERS
    f32x4 sa[2][2];              // [qs][n]
#pragma unroll
    for (int qs = 0; qs < 2; ++qs)
#pragma unroll
      for (int n = 0; n < 2; ++n) sa[qs][n] = (f32x4){0.f,0.f,0.f,0.f};
#pragma unroll
    for (int n = 0; n < 2; ++n) {
#pragma unroll
      for (int dh = 0; dh < 2; ++dh) {
#pragma unroll
        for (int qs = 0; qs < 2; ++qs) {
          sa[qs][n] = __builtin_amdgcn_mfma_f32_16x16x32_bf16(kfh[n][dh], qfh[qs][dh], sa[qs][n], 0, 0, 0);
          sa[qs][n] = __builtin_amdgcn_mfma_f32_16x16x32_bf16(kfh[n][dh], qfm[qs][dh], sa[qs][n], 0, 0, 0);
          sa[qs][n] = __builtin_amdgcn_mfma_f32_16x16x32_bf16(kfm[n][dh], qfh[qs][dh], sa[qs][n], 0, 0, 0);
          sa[qs][n] = __builtin_amdgcn_mfma_f32_16x16x32_bf16(kfh[n][dh], qfl[qs][dh], sa[qs][n], 0, 0, 0);
          sa[qs][n] = __builtin_amdgcn_mfma_f32_16x16x32_bf16(kfm[n][dh], qfm[qs][dh], sa[qs][n], 0, 0, 0);
          sa[qs][n] = __builtin_amdgcn_mfma_f32_16x16x32_bf16(kfl[n][dh], qfh[qs][dh], sa[qs][n], 0, 0, 0);
        }
      }
    }
    // prefetch next tile's K frags (regs now dead) + V regs; latency hides under
    // softmax+PV (~1500 cyc >> L2 ~200 cyc)
    if (kt + 1 < NT) {
      const size_t kb = kfbase + (size_t)(kt+1) * 64 * 64;
#pragma unroll
      for (int n = 0; n < 2; ++n)
#pragma unroll
        for (int dh = 0; dh < 2; ++dh) {
          size_t ko = kb + (size_t)(n*16) * 64 + dh*32;
          kfh[n][dh] = *(const short8*)(Kph + ko);
          kfm[n][dh] = *(const short8*)(Kpm + ko);
          kfl[n][dh] = *(const short8*)(Kpl + ko);
        }
      size_t vo = (size_t)srow * SEQ + (kt+1)*64 + scol;
      rvh = *(const short8*)(Vph + vo);
      rvm = *(const short8*)(Vpm + vo);
    }
    // NO-MAX softmax (validated); P -> 2 truncation planes (rel err < 2^-16)
#pragma unroll
    for (int qs = 0; qs < 2; ++qs) {
#pragma unroll
      for (int n = 0; n < 2; ++n) {
        short hh[4], mm[4];
#pragma unroll
        for (int r = 0; r < 4; ++r) {
          float p = __expf(sa[qs][n][r]);
          lacc[qs] += p;
          split2_bits(p, &hh[r], &mm[r]);
        }
        const int prow = wq*32 + qs*16 + r16;
        const int pcol = wk*32 + n*16 + g*4;
        short4v vh4; vh4[0]=hh[0]; vh4[1]=hh[1]; vh4[2]=hh[2]; vh4[3]=hh[3];
        short4v vm4; vm4[0]=mm[0]; vm4[1]=mm[1]; vm4[2]=mm[2]; vm4[3]=mm[3];
        *(short4v*)&Pth[prow][pcol] = vh4;
        *(short4v*)&Ptm[prow][pcol] = vm4;
      }
    }
    asm volatile("s_waitcnt lgkmcnt(15)" ::: "memory");   // compiler-order fence (R18)
    __builtin_amdgcn_sched_barrier(0);
    // PV: 3-term (ph*vh + ph*vm + pm*vh), 2-plane P and V
    short8 aph[2], apm[2];
#pragma unroll
    for (int qs = 0; qs < 2; ++qs) {
      aph[qs] = *(const short8*)&Pth[wq*32 + qs*16 + r16][wk*32 + g*8];
      apm[qs] = *(const short8*)&Ptm[wq*32 + qs*16 + r16][wk*32 + g*8];
    }
#pragma unroll
    for (int ne = 0; ne < 4; ++ne) {
      short8 bvh = *(const short8*)&Vth[ne*16 + r16][wk*32 + g*8];
      short8 bvm = *(const short8*)&Vtm[ne*16 + r16][wk*32 + g*8];
#pragma unroll
      for (int qs = 0; qs < 2; ++qs) {
        o[qs][ne] = __builtin_amdgcn_mfma_f32_16x16x32_bf16(aph[qs], bvh, o[qs][ne], 0, 0, 0);
        o[qs][ne] = __builtin_amdgcn_mfma_f32_16x16x32_bf16(aph[qs], bvm, o[qs][ne], 0, 0, 0);
        o[qs][ne] = __builtin_amdgcn_mfma_f32_16x16x32_bf16(apm[qs], bvh, o[qs][ne], 0, 0, 0);
      }
    }
  }

  // l: reduce over g groups -> full partial for this wk half
  float lr[2];
#pragma unroll
  for (int qs = 0; qs < 2; ++qs) {
    float s = lacc[qs];
    s += __shfl_xor(s, 16);
    s += __shfl_xor(s, 32);
    lr[qs] = s;
  }

  // ---- combine wk halves via Pt planes (validated: barriers + same-typed reuse) ----
  __syncthreads();                 // all tile-loop LDS reads done
#pragma unroll
  for (int qs = 0; qs < 2; ++qs)
    split3(lr[qs], &Pth[wq*32 + qs*16 + r16][64 + wk],
                   &Ptm[wq*32 + qs*16 + r16][64 + wk],
                   &Ptl[wq*32 + qs*16 + r16][64 + wk]);
  if (wk == 1) {
#pragma unroll
    for (int qs = 0; qs < 2; ++qs)
#pragma unroll
      for (int ne = 0; ne < 4; ++ne)
#pragma unroll
        for (int r = 0; r < 4; ++r) {
          int row = wq*32 + qs*16 + g*4 + r, col = ne*16 + r16;
          split3(o[qs][ne][r], &Pth[row][col], &Ptm[row][col], &Ptl[row][col]);
        }
  }
  __syncthreads();
  float lt[2][4];
  if (wk == 0) {
#pragma unroll
    for (int qs = 0; qs < 2; ++qs) {
#pragma unroll
      for (int ne = 0; ne < 4; ++ne)
#pragma unroll
        for (int r = 0; r < 4; ++r) {
          int row = wq*32 + qs*16 + g*4 + r, col = ne*16 + r16;
          o[qs][ne][r] += bf2f(Pth[row][col]) + bf2f(Ptm[row][col]) + bf2f(Ptl[row][col]);
        }
#pragma unroll
      for (int r = 0; r < 4; ++r) {
        int row = wq*32 + qs*16 + g*4 + r;
        lt[qs][r] = bf2f(Pth[row][64]) + bf2f(Ptm[row][64]) + bf2f(Ptl[row][64])
                  + bf2f(Pth[row][65]) + bf2f(Ptm[row][65]) + bf2f(Ptl[row][65]);
      }
    }
  }
  asm volatile("s_waitcnt lgkmcnt(0)" ::: "memory");
  __builtin_amdgcn_sched_barrier(0);

  if (wk == 0) {
    // ctx -> Pth/Ptl split2, fence, fc MFMA (B direct from Wfc), LN, store (validated)
#pragma unroll
    for (int qs = 0; qs < 2; ++qs)
#pragma unroll
      for (int ne = 0; ne < 4; ++ne)
#pragma unroll
        for (int r = 0; r < 4; ++r) {
          int row = wq*32 + qs*16 + g*4 + r, col = ne*16 + r16;
          split2(o[qs][ne][r] / lt[qs][r], &Pth[row][col], &Ptl[row][col]);
        }
    asm volatile("s_waitcnt lgkmcnt(0)" ::: "memory");
    __builtin_amdgcn_sched_barrier(0);
#pragma unroll
    for (int qs = 0; qs < 2; ++qs) {
      short8 cah[2], cal[2];
#pragma unroll
      for (int ks = 0; ks < 2; ++ks) {
        cah[ks] = *(const short8*)&Pth[wq*32 + qs*16 + r16][ks*32 + g*8];
        cal[ks] = *(const short8*)&Ptl[wq*32 + qs*16 + r16][ks*32 + g*8];
      }
      float res[4][4];
      float sum[4], sq[4];
#pragma unroll
      for (int r = 0; r < 4; ++r) { sum[r] = 0.f; sq[r] = 0.f; }
#pragma unroll
      for (int n = 0; n < 4; ++n) {
        const float* wrow = Wfc + (n*16 + r16) * 64;
        f32x4 fca = (f32x4){0.f,0.f,0.f,0.f};
#pragma unroll
        for (int ks = 0; ks < 2; ++ks) {
          float4 w0 = *(const float4*)(wrow + ks*32 + g*8);
          float4 w1 = *(const float4*)(wrow + ks*32 + g*8 + 4);
          short8 bh, bl;
          short2 s0 = split2v(w0.x); bh[0] = s0.x; bl[0] = s0.y;
          short2 s1 = split2v(w0.y); bh[1] = s1.x; bl[1] = s1.y;
          short2 s2 = split2v(w0.z); bh[2] = s2.x; bl[2] = s2.y;
          short2 s3 = split2v(w0.w); bh[3] = s3.x; bl[3] = s3.y;
          short2 s4 = split2v(w1.x); bh[4] = s4.x; bl[4] = s4.y;
          short2 s5 = split2v(w1.y); bh[5] = s5.x; bl[5] = s5.y;
          short2 s6 = split2v(w1.z); bh[6] = s6.x; bl[6] = s6.y;
          short2 s7 = split2v(w1.w); bh[7] = s7.x; bl[7] = s7.y;
          fca = __builtin_amdgcn_mfma_f32_16x16x32_bf16(cah[ks], bh, fca, 0, 0, 0);
          fca = __builtin_amdgcn_mfma_f32_16x16x32_bf16(cah[ks], bl, fca, 0, 0, 0);
          fca = __builtin_amdgcn_mfma_f32_16x16x32_bf16(cal[ks], bh, fca, 0, 0, 0);
        }
#pragma unroll
        for (int r = 0; r < 4; ++r) {
          float v = fca[r] +
            x[((size_t)head * SEQ + q0 + wq*32 + qs*16 + g*4 + r) * 64 + n*16 + r16];
          res[n][r] = v;
          sum[r] += v;
          sq[r]  += v * v;
        }
      }
#pragma unroll
      for (int r = 0; r < 4; ++r) {
        float s = sum[r], q2 = sq[r];
        s += __shfl_xor(s, 1);  q2 += __shfl_xor(q2, 1);
        s += __shfl_xor(s, 2);  q2 += __shfl_xor(q2, 2);
        s += __shfl_xor(s, 4);  q2 += __shfl_xor(q2, 4);
        s += __shfl_xor(s, 8);  q2 += __shfl_xor(q2, 8);
        float mean = s * (1.f/64.f);
        float var  = q2 * (1.f/64.f) - mean * mean;
        float rstd = rsqrtf(var + 1e-5f);
        float* op = out + ((size_t)head * SEQ + q0 + wq*32 + qs*16 + g*4 + r) * 64 + r16;
#pragma unroll
        for (int n = 0; n < 4; ++n)
          op[n*16] = (res[n][r] - mean) * rstd;
      }
    }
  }
}

extern "C" void kernel_launch(void* const* d_in, const int* in_sizes, int n_in,
                              void* d_out, int out_size, void* d_ws, size_t ws_size,
                              hipStream_t stream) {
  const float* x  = (const float*)d_in[0];
  const float* WQ = (const float*)d_in[1];
  const float* WK = (const float*)d_in[2];
  const float* WV = (const float*)d_in[3];
  const float* Wf = (const float*)d_in[4];
  float* out = (float*)d_out;
  (void)d_ws; (void)ws_size; (void)in_sizes; (void)n_in; (void)out_size;
  qkv_valu<<<dim3(512), dim3(256), 0, stream>>>(x, WQ, WK, WV);
  attn_mfma<<<dim3(256), dim3(512), 0, stream>>>(x, Wf, out);
}

// Round 23
// 100.795 us; speedup vs baseline: 1.4697x; 1.4697x over previous
//
#include <hip/hip_runtime.h>
#include <math.h>

// AttentionLayer: x[16,2048,64] f32 -> QKV -> softmax(QK^T/8)V -> fc+residual -> LN.
// REVERT to R21 (best validated: 101.0us total, K2=89.0us). R22's K-frag global
// prefetch regressed 1.5x (L2-latency-serial, same mode as R15) -- LDS staging with
// reg double-buffer is the equilibrium transport. Structure: 2x4 wave split, swapped
// QK^T 6-term (f32-faithful scores), 3-term PV (2-plane P/V), NO-MAX softmax,
// XCD-swizzled blocks (L2-fit per XCD), MFMA fc epilogue. 515-validated numerics.

#define HEADS 16
#define SEQ   2048
#define DIM   64
#define NT    32

typedef short short8 __attribute__((ext_vector_type(8)));   // 8 x bf16 bits
typedef short short4v __attribute__((ext_vector_type(4)));
typedef float f32x4  __attribute__((ext_vector_type(4)));

// 32 MB module scratch, fully rewritten by K1 every launch (replay-deterministic).
__device__ __align__(16) short g_Qh [(size_t)HEADS * SEQ * DIM];
__device__ __align__(16) short g_Qm [(size_t)HEADS * SEQ * DIM];
__device__ __align__(16) short g_Ql [(size_t)HEADS * SEQ * DIM];
__device__ __align__(16) short g_Kh [(size_t)HEADS * SEQ * DIM];
__device__ __align__(16) short g_Km [(size_t)HEADS * SEQ * DIM];
__device__ __align__(16) short g_Kl [(size_t)HEADS * SEQ * DIM];
__device__ __align__(16) short g_VTh[(size_t)HEADS * DIM * SEQ];   // V^T [head][e][s]
__device__ __align__(16) short g_VTm[(size_t)HEADS * DIM * SEQ];

static __device__ __forceinline__ short f2bf(float f) {
  union { float f; unsigned u; } cv; cv.f = f;
  unsigned u = cv.u;
  unsigned r = (u + 0x7fffu + ((u >> 16) & 1u)) >> 16;   // RNE
  return (short)r;
}
static __device__ __forceinline__ float bf2f(short s) {
  union { unsigned u; float f; } cv; cv.u = ((unsigned)(unsigned short)s) << 16;
  return cv.f;
}
static __device__ __forceinline__ void split2(float v, short* h, short* l) {
  short hh = f2bf(v);
  *h = hh;
  *l = f2bf(v - bf2f(hh));
}
static __device__ __forceinline__ short2 split2v(float v) {
  short hh = f2bf(v);
  short ll = f2bf(v - bf2f(hh));
  return make_short2(hh, ll);
}
// EXACT: v == h+m+l for normal-range f32 (24 = 8+8+8 mantissa bits).
static __device__ __forceinline__ void split3(float v, short* h, short* m, short* l) {
  short hh = f2bf(v);
  float r  = v - bf2f(hh);
  short mm = f2bf(r);
  *h = hh; *m = mm;
  *l = f2bf(r - bf2f(mm));
}
// 2-plane truncation split (~3 VALU): v = h + m + O(2^-16 v).
static __device__ __forceinline__ void split2_bits(float v, short* h, short* m) {
  union { float f; unsigned u; } a; a.f = v;
  unsigned hu = a.u & 0xFFFF0000u;
  union { unsigned u; float f; } hf; hf.u = hu;
  union { float f; unsigned u; } b; b.f = v - hf.f;     // exact residual
  *h = (short)(hu >> 16); *m = (short)(b.u >> 16);
}

// ---------------- K1: fp32 VALU projections (validated), split writeout --------------
__global__ __launch_bounds__(256) void qkv_valu(
    const float* __restrict__ x,  const float* __restrict__ WQ,
    const float* __restrict__ WK, const float* __restrict__ WV)
{
  __shared__ float XB [64][68];
  __shared__ float WTQ[64][68];
  __shared__ float WTK[64][68];
  __shared__ float WTV[64][68];
  const int t    = threadIdx.x;
  const int bid  = (int)(blockIdx.x & 7) * 64 + (int)(blockIdx.x >> 3);  // XCD swizzle (512%8==0)
  const int head = bid >> 5;
  const int s0   = (bid & 31) * 64;
  const float* xp = x + ((size_t)head * SEQ + s0) * DIM;

  for (int i = t; i < 1024; i += 256) {
    int row = i >> 4, c4 = (i & 15) << 2;
    *(float4*)&XB[row][c4] = *(const float4*)(xp + row * 64 + c4);
    float4 a = *(const float4*)(WQ + row * 64 + c4);
    WTQ[c4][row] = a.x; WTQ[c4+1][row] = a.y; WTQ[c4+2][row] = a.z; WTQ[c4+3][row] = a.w;
    float4 b = *(const float4*)(WK + row * 64 + c4);
    WTK[c4][row] = b.x; WTK[c4+1][row] = b.y; WTK[c4+2][row] = b.z; WTK[c4+3][row] = b.w;
    float4 d = *(const float4*)(WV + row * 64 + c4);
    WTV[c4][row] = d.x; WTV[c4+1][row] = d.y; WTV[c4+2][row] = d.z; WTV[c4+3][row] = d.w;
  }
  __syncthreads();

  const int jj = t >> 2;
  const int eg = (t & 3) * 16;
  float aq[16], ak[16], av[16];
#pragma unroll
  for (int c = 0; c < 16; ++c) { aq[c] = 0.f; ak[c] = 0.f; av[c] = 0.f; }
  for (int d = 0; d < 64; ++d) {
    float xv = XB[jj][d];
#pragma unroll
    for (int c4 = 0; c4 < 16; c4 += 4) {
      float4 wq = *(const float4*)&WTQ[d][eg + c4];
      aq[c4]   += xv * wq.x; aq[c4+1] += xv * wq.y; aq[c4+2] += xv * wq.z; aq[c4+3] += xv * wq.w;
      float4 wk = *(const float4*)&WTK[d][eg + c4];
      ak[c4]   += xv * wk.x; ak[c4+1] += xv * wk.y; ak[c4+2] += xv * wk.z; ak[c4+3] += xv * wk.w;
      float4 wv = *(const float4*)&WTV[d][eg + c4];
      av[c4]   += xv * wv.x; av[c4+1] += xv * wv.y; av[c4+2] += xv * wv.z; av[c4+3] += xv * wv.w;
    }
  }
  const size_t rowi  = ((size_t)head * SEQ + s0 + jj) * DIM + eg;
  const size_t vbase = (size_t)head * DIM * SEQ + s0 + jj;
  short qh_[16], qm_[16], ql_[16], kh_[16], km_[16], kl_[16];
#pragma unroll
  for (int c = 0; c < 16; ++c) {
    split3(aq[c] * 0.125f, &qh_[c], &qm_[c], &ql_[c]);
    split3(ak[c],          &kh_[c], &km_[c], &kl_[c]);
    size_t vb = vbase + (size_t)(eg + c) * SEQ;
    split2(av[c], &g_VTh[vb], &g_VTm[vb]);      // V needs only 2 planes (PV 3-term)
  }
#pragma unroll
  for (int half = 0; half < 2; ++half) {
    *(short8*)(g_Qh + rowi + half*8) = *(const short8*)&qh_[half*8];
    *(short8*)(g_Qm + rowi + half*8) = *(const short8*)&qm_[half*8];
    *(short8*)(g_Ql + rowi + half*8) = *(const short8*)&ql_[half*8];
    *(short8*)(g_Kh + rowi + half*8) = *(const short8*)&kh_[half*8];
    *(short8*)(g_Km + rowi + half*8) = *(const short8*)&km_[half*8];
    *(short8*)(g_Kl + rowi + half*8) = *(const short8*)&kl_[half*8];
  }
}

// -------- K2: flash attention (2x4 wave split, swapped QK^T, 3-term PV) + fc + LN --------
__global__ __launch_bounds__(512) void attn_mfma(
    const float* __restrict__ x, const float* __restrict__ Wfc, float* __restrict__ out)
{
  __shared__ short Kth[64][72],  Ktm[64][72],  Ktl[64][72];   // K tile planes [key][e]
  __shared__ short Vth[64][72],  Vtm[64][72];                 // V^T tile planes [e][key]
  __shared__ short Pth[128][72], Ptm[128][72], Ptl[128][72];  // P(h,m) | combine | ctx
  const int t    = threadIdx.x;
  const int w    = t >> 6, lane = t & 63;
  const int r16  = lane & 15, g = lane >> 4;
  const int wq   = w & 3;          // q sub-block (32 rows)
  const int wk   = (w >> 2) & 1;   // key half (32 keys)
  const int bid  = (int)(blockIdx.x & 7) * 32 + (int)(blockIdx.x >> 3);  // XCD swizzle:
  const int head = bid >> 4;       // each XCD owns 2 whole heads (~4MB = L2-fit)
  const int q0   = (bid & 15) * 128;
  const short* Kph = g_Kh  + (size_t)head * SEQ * DIM;
  const short* Kpm = g_Km  + (size_t)head * SEQ * DIM;
  const short* Kpl = g_Kl  + (size_t)head * SEQ * DIM;
  const short* Vph = g_VTh + (size_t)head * DIM * SEQ;
  const short* Vpm = g_VTm + (size_t)head * DIM * SEQ;
  const int srow = t >> 3, scol = (t & 7) * 8;

  // Q B-frags (col=q=r16, k=e): direct from global planes (validated pattern)
  short8 qfh[2][2], qfm[2][2], qfl[2][2];   // [qs][dh]
#pragma unroll
  for (int qs = 0; qs < 2; ++qs) {
    const size_t qrow = ((size_t)head * SEQ + q0 + wq*32 + qs*16 + r16) * DIM;
#pragma unroll
    for (int dh = 0; dh < 2; ++dh) {
      qfh[qs][dh] = *(const short8*)(g_Qh + qrow + dh*32 + g*8);
      qfm[qs][dh] = *(const short8*)(g_Qm + qrow + dh*32 + g*8);
      qfl[qs][dh] = *(const short8*)(g_Ql + qrow + dh*32 + g*8);
    }
  }

  // prologue: prefetch tile 0 into regs
  short8 rkh, rkm, rkl, rvh, rvm;
  {
    size_t ko = (size_t)srow * 64 + scol;
    rkh = *(const short8*)(Kph + ko);
    rkm = *(const short8*)(Kpm + ko);
    rkl = *(const short8*)(Kpl + ko);
    size_t vo = (size_t)srow * SEQ + scol;
    rvh = *(const short8*)(Vph + vo);
    rvm = *(const short8*)(Vpm + vo);
  }

  f32x4 o[2][4];                 // [qs][ne]
  float lacc[2];
#pragma unroll
  for (int qs = 0; qs < 2; ++qs) {
    lacc[qs] = 0.f;
#pragma unroll
    for (int ne = 0; ne < 4; ++ne) o[qs][ne] = (f32x4){0.f,0.f,0.f,0.f};
  }

  for (int kt = 0; kt < NT; ++kt) {
    __syncthreads();
    *(short8*)&Kth[srow][scol] = rkh;
    *(short8*)&Ktm[srow][scol] = rkm;
    *(short8*)&Ktl[srow][scol] = rkl;
    *(short8*)&Vth[srow][scol] = rvh;
    *(short8*)&Vtm[srow][scol] = rvm;
    __syncthreads();
    if (kt + 1 < NT) {                            // prefetch next tile (overlaps compute)
      size_t ko = (size_t)((kt+1)*64 + srow) * 64 + scol;
      rkh = *(const short8*)(Kph + ko);
      rkm = *(const short8*)(Kpm + ko);
      rkl = *(const short8*)(Kpl + ko);
      size_t vo = (size_t)srow * SEQ + (kt+1)*64 + scol;
      rvh = *(const short8*)(Vph + vo);
      rvm = *(const short8*)(Vpm + vo);
    }

    // swapped QK^T: 6-term (R10-validated; scores need f32 fidelity)
    f32x4 sa[2][2];              // [qs][n]
#pragma unroll
    for (int qs = 0; qs < 2; ++qs)
#pragma unroll
      for (int n = 0; n < 2; ++n) sa[qs][n] = (f32x4){0.f,0.f,0.f,0.f};
#pragma unroll
    for (int n = 0; n < 2; ++n) {
#pragma unroll
      for (int dh = 0; dh < 2; ++dh) {
        short8 akh = *(const short8*)&Kth[wk*32 + n*16 + r16][dh*32 + g*8];
        short8 akm = *(const short8*)&Ktm[wk*32 + n*16 + r16][dh*32 + g*8];
        short8 akl = *(const short8*)&Ktl[wk*32 + n*16 + r16][dh*32 + g*8];
#pragma unroll
        for (int qs = 0; qs < 2; ++qs) {
          sa[qs][n] = __builtin_amdgcn_mfma_f32_16x16x32_bf16(akh, qfh[qs][dh], sa[qs][n], 0, 0, 0);
          sa[qs][n] = __builtin_amdgcn_mfma_f32_16x16x32_bf16(akh, qfm[qs][dh], sa[qs][n], 0, 0, 0);
          sa[qs][n] = __builtin_amdgcn_mfma_f32_16x16x32_bf16(akm, qfh[qs][dh], sa[qs][n], 0, 0, 0);
          sa[qs][n] = __builtin_amdgcn_mfma_f32_16x16x32_bf16(akh, qfl[qs][dh], sa[qs][n], 0, 0, 0);
          sa[qs][n] = __builtin_amdgcn_mfma_f32_16x16x32_bf16(akm, qfm[qs][dh], sa[qs][n], 0, 0, 0);
          sa[qs][n] = __builtin_amdgcn_mfma_f32_16x16x32_bf16(akl, qfh[qs][dh], sa[qs][n], 0, 0, 0);
        }
      }
    }
    // NO-MAX softmax (validated); P -> 2 truncation planes (rel err < 2^-16)
#pragma unroll
    for (int qs = 0; qs < 2; ++qs) {
#pragma unroll
      for (int n = 0; n < 2; ++n) {
        short hh[4], mm[4];
#pragma unroll
        for (int r = 0; r < 4; ++r) {
          float p = __expf(sa[qs][n][r]);
          lacc[qs] += p;
          split2_bits(p, &hh[r], &mm[r]);
        }
        const int prow = wq*32 + qs*16 + r16;
        const int pcol = wk*32 + n*16 + g*4;
        short4v vh4; vh4[0]=hh[0]; vh4[1]=hh[1]; vh4[2]=hh[2]; vh4[3]=hh[3];
        short4v vm4; vm4[0]=mm[0]; vm4[1]=mm[1]; vm4[2]=mm[2]; vm4[3]=mm[3];
        *(short4v*)&Pth[prow][pcol] = vh4;
        *(short4v*)&Ptm[prow][pcol] = vm4;
      }
    }
    asm volatile("s_waitcnt lgkmcnt(15)" ::: "memory");   // compiler-order fence (R18)
    __builtin_amdgcn_sched_barrier(0);
    // PV: 3-term (ph*vh + ph*vm + pm*vh), 2-plane P and V
    short8 aph[2], apm[2];
#pragma unroll
    for (int qs = 0; qs < 2; ++qs) {
      aph[qs] = *(const short8*)&Pth[wq*32 + qs*16 + r16][wk*32 + g*8];
      apm[qs] = *(const short8*)&Ptm[wq*32 + qs*16 + r16][wk*32 + g*8];
    }
#pragma unroll
    for (int ne = 0; ne < 4; ++ne) {
      short8 bvh = *(const short8*)&Vth[ne*16 + r16][wk*32 + g*8];
      short8 bvm = *(const short8*)&Vtm[ne*16 + r16][wk*32 + g*8];
#pragma unroll
      for (int qs = 0; qs < 2; ++qs) {
        o[qs][ne] = __builtin_amdgcn_mfma_f32_16x16x32_bf16(aph[qs], bvh, o[qs][ne], 0, 0, 0);
        o[qs][ne] = __builtin_amdgcn_mfma_f32_16x16x32_bf16(aph[qs], bvm, o[qs][ne], 0, 0, 0);
        o[qs][ne] = __builtin_amdgcn_mfma_f32_16x16x32_bf16(apm[qs], bvh, o[qs][ne], 0, 0, 0);
      }
    }
  }

  // l: reduce over g groups -> full partial for this wk half
  float lr[2];
#pragma unroll
  for (int qs = 0; qs < 2; ++qs) {
    float s = lacc[qs];
    s += __shfl_xor(s, 16);
    s += __shfl_xor(s, 32);
    lr[qs] = s;
  }

  // ---- combine wk halves via Pt planes (validated: barriers + same-typed reuse) ----
  __syncthreads();                 // all tile-loop LDS reads done
#pragma unroll
  for (int qs = 0; qs < 2; ++qs)
    split3(lr[qs], &Pth[wq*32 + qs*16 + r16][64 + wk],
                   &Ptm[wq*32 + qs*16 + r16][64 + wk],
                   &Ptl[wq*32 + qs*16 + r16][64 + wk]);
  if (wk == 1) {
#pragma unroll
    for (int qs = 0; qs < 2; ++qs)
#pragma unroll
      for (int ne = 0; ne < 4; ++ne)
#pragma unroll
        for (int r = 0; r < 4; ++r) {
          int row = wq*32 + qs*16 + g*4 + r, col = ne*16 + r16;
          split3(o[qs][ne][r], &Pth[row][col], &Ptm[row][col], &Ptl[row][col]);
        }
  }
  __syncthreads();
  float lt[2][4];
  if (wk == 0) {
#pragma unroll
    for (int qs = 0; qs < 2; ++qs) {
#pragma unroll
      for (int ne = 0; ne < 4; ++ne)
#pragma unroll
        for (int r = 0; r < 4; ++r) {
          int row = wq*32 + qs*16 + g*4 + r, col = ne*16 + r16;
          o[qs][ne][r] += bf2f(Pth[row][col]) + bf2f(Ptm[row][col]) + bf2f(Ptl[row][col]);
        }
#pragma unroll
      for (int r = 0; r < 4; ++r) {
        int row = wq*32 + qs*16 + g*4 + r;
        lt[qs][r] = bf2f(Pth[row][64]) + bf2f(Ptm[row][64]) + bf2f(Ptl[row][64])
                  + bf2f(Pth[row][65]) + bf2f(Ptm[row][65]) + bf2f(Ptl[row][65]);
      }
    }
  }
  asm volatile("s_waitcnt lgkmcnt(0)" ::: "memory");
  __builtin_amdgcn_sched_barrier(0);

  if (wk == 0) {
    // ctx -> Pth/Ptl split2, fence, fc MFMA (B direct from Wfc), LN, store (validated)
#pragma unroll
    for (int qs = 0; qs < 2; ++qs)
#pragma unroll
      for (int ne = 0; ne < 4; ++ne)
#pragma unroll
        for (int r = 0; r < 4; ++r) {
          int row = wq*32 + qs*16 + g*4 + r, col = ne*16 + r16;
          split2(o[qs][ne][r] / lt[qs][r], &Pth[row][col], &Ptl[row][col]);
        }
    asm volatile("s_waitcnt lgkmcnt(0)" ::: "memory");
    __builtin_amdgcn_sched_barrier(0);
#pragma unroll
    for (int qs = 0; qs < 2; ++qs) {
      short8 cah[2], cal[2];
#pragma unroll
      for (int ks = 0; ks < 2; ++ks) {
        cah[ks] = *(const short8*)&Pth[wq*32 + qs*16 + r16][ks*32 + g*8];
        cal[ks] = *(const short8*)&Ptl[wq*32 + qs*16 + r16][ks*32 + g*8];
      }
      float res[4][4];
      float sum[4], sq[4];
#pragma unroll
      for (int r = 0; r < 4; ++r) { sum[r] = 0.f; sq[r] = 0.f; }
#pragma unroll
      for (int n = 0; n < 4; ++n) {
        const float* wrow = Wfc + (n*16 + r16) * 64;
        f32x4 fca = (f32x4){0.f,0.f,0.f,0.f};
#pragma unroll
        for (int ks = 0; ks < 2; ++ks) {
          float4 w0 = *(const float4*)(wrow + ks*32 + g*8);
          float4 w1 = *(const float4*)(wrow + ks*32 + g*8 + 4);
          short8 bh, bl;
          short2 s0 = split2v(w0.x); bh[0] = s0.x; bl[0] = s0.y;
          short2 s1 = split2v(w0.y); bh[1] = s1.x; bl[1] = s1.y;
          short2 s2 = split2v(w0.z); bh[2] = s2.x; bl[2] = s2.y;
          short2 s3 = split2v(w0.w); bh[3] = s3.x; bl[3] = s3.y;
          short2 s4 = split2v(w1.x); bh[4] = s4.x; bl[4] = s4.y;
          short2 s5 = split2v(w1.y); bh[5] = s5.x; bl[5] = s5.y;
          short2 s6 = split2v(w1.z); bh[6] = s6.x; bl[6] = s6.y;
          short2 s7 = split2v(w1.w); bh[7] = s7.x; bl[7] = s7.y;
          fca = __builtin_amdgcn_mfma_f32_16x16x32_bf16(cah[ks], bh, fca, 0, 0, 0);
          fca = __builtin_amdgcn_mfma_f32_16x16x32_bf16(cah[ks], bl, fca, 0, 0, 0);
          fca = __builtin_amdgcn_mfma_f32_16x16x32_bf16(cal[ks], bh, fca, 0, 0, 0);
        }
#pragma unroll
        for (int r = 0; r < 4; ++r) {
          float v = fca[r] +
            x[((size_t)head * SEQ + q0 + wq*32 + qs*16 + g*4 + r) * 64 + n*16 + r16];
          res[n][r] = v;
          sum[r] += v;
          sq[r]  += v * v;
        }
      }
#pragma unroll
      for (int r = 0; r < 4; ++r) {
        float s = sum[r], q2 = sq[r];
        s += __shfl_xor(s, 1);  q2 += __shfl_xor(q2, 1);
        s += __shfl_xor(s, 2);  q2 += __shfl_xor(q2, 2);
        s += __shfl_xor(s, 4);  q2 += __shfl_xor(q2, 4);
        s += __shfl_xor(s, 8);  q2 += __shfl_xor(q2, 8);
        float mean = s * (1.f/64.f);
        float var  = q2 * (1.f/64.f) - mean * mean;
        float rstd = rsqrtf(var + 1e-5f);
        float* op = out + ((size_t)head * SEQ + q0 + wq*32 + qs*16 + g*4 + r) * 64 + r16;
#pragma unroll
        for (int n = 0; n < 4; ++n)
          op[n*16] = (res[n][r] - mean) * rstd;
      }
    }
  }
}

extern "C" void kernel_launch(void* const* d_in, const int* in_sizes, int n_in,
                              void* d_out, int out_size, void* d_ws, size_t ws_size,
                              hipStream_t stream) {
  const float* x  = (const float*)d_in[0];
  const float* WQ = (const float*)d_in[1];
  const float* WK = (const float*)d_in[2];
  const float* WV = (const float*)d_in[3];
  const float* Wf = (const float*)d_in[4];
  float* out = (float*)d_out;
  (void)d_ws; (void)ws_size; (void)in_sizes; (void)n_in; (void)out_size;
  qkv_valu<<<dim3(512), dim3(256), 0, stream>>>(x, WQ, WK, WV);
  attn_mfma<<<dim3(256), dim3(512), 0, stream>>>(x, Wf, out);
}